// Round 15
// baseline (180.914 us; speedup 1.0000x reference)
//
#include <hip/hip_runtime.h>

typedef __bf16 bf16_t;
typedef __bf16 bf16x8 __attribute__((ext_vector_type(8)));
typedef float  f32x4  __attribute__((ext_vector_type(4)));
typedef unsigned int u32x4 __attribute__((ext_vector_type(4)));

// problem constants
// B=2 C=1280 HEADS=20 DH=64 S=4096 L=77 ENC=4096 GROUPS=32 EPS=1e-5

// ---------------- fat prep kernel: 4 transposes + gn_partial + layernorm -----
__global__ __launch_bounds__(256) void k_prep(
    const float* __restrict__ x, const float* __restrict__ text,
    const float* __restrict__ lng, const float* __restrict__ lnb,
    const float* __restrict__ w0, const float* __restrict__ w1,
    const float* __restrict__ w2, const float* __restrict__ w3,
    bf16_t* __restrict__ o0, bf16_t* __restrict__ o1,
    bf16_t* __restrict__ o2, bf16_t* __restrict__ o3,
    float* __restrict__ partial, bf16_t* __restrict__ enc)
{
  __shared__ float smemf[64 * 33];
  const int bid = blockIdx.x;
  const int t   = threadIdx.x;

  if (bid < 6720) {
    int z, lb;
    if      (bid < 800)  { z = 0; lb = bid; }
    else if (bid < 1600) { z = 1; lb = bid - 800; }
    else if (bid < 4160) { z = 2; lb = bid - 1600; }
    else                 { z = 3; lb = bid - 4160; }
    const float* in  = (z == 0) ? w0 : (z == 1) ? w1 : (z == 2) ? w2 : w3;
    bf16_t*      out = (z == 0) ? o0 : (z == 1) ? o1 : (z == 2) ? o2 : o3;
    const int R  = (z < 2) ? 1280 : 4096;
    const int c0 = (lb % 40) * 32;
    const int r0 = (lb / 40) * 64;
    float (*tile)[33] = (float(*)[33])smemf;
#pragma unroll
    for (int it = 0; it < 8; ++it) {
      int r = it * 8 + (t >> 5), c = t & 31;
      tile[r][c] = in[(size_t)(r0 + r) * 1280 + c0 + c];
    }
    __syncthreads();
    const int oc  = t >> 3;
    const int seg = t & 7;
    bf16x8 o;
#pragma unroll
    for (int e = 0; e < 8; ++e) o[e] = (bf16_t)tile[seg * 8 + e][oc];
    *(bf16x8*)(out + (size_t)(c0 + oc) * R + r0 + seg * 8) = o;
  } else if (bid < 8768) {
    const int pb    = bid - 6720;
    const int bg    = pb >> 5;
    const int chunk = pb & 31;
    const float* p  = x + (size_t)bg * 163840 + (size_t)chunk * 5120;
    float s1 = 0.f, s2 = 0.f;
#pragma unroll
    for (int it = 0; it < 5; ++it) {
      float4 v = *(const float4*)(p + (size_t)(it * 256 + t) * 4);
      s1 += v.x + v.y + v.z + v.w;
      s2 += v.x * v.x + v.y * v.y + v.z * v.z + v.w * v.w;
    }
#pragma unroll
    for (int off = 32; off > 0; off >>= 1) {
      s1 += __shfl_down(s1, off);
      s2 += __shfl_down(s2, off);
    }
    float* r1 = smemf;
    float* r2 = smemf + 4;
    if ((t & 63) == 0) { r1[t >> 6] = s1; r2[t >> 6] = s2; }
    __syncthreads();
    if (t == 0) {
      partial[pb * 2]     = r1[0] + r1[1] + r1[2] + r1[3];
      partial[pb * 2 + 1] = r2[0] + r2[1] + r2[2] + r2[3];
    }
  } else {
    const int row = bid - 8768;
    const float* p = text + (size_t)row * 4096;
    float s1 = 0.f, s2 = 0.f;
    for (int i = t; i < 1024; i += 256) {
      float4 v = *(const float4*)(p + (size_t)i * 4);
      s1 += v.x + v.y + v.z + v.w;
      s2 += v.x * v.x + v.y * v.y + v.z * v.z + v.w * v.w;
    }
#pragma unroll
    for (int off = 32; off > 0; off >>= 1) {
      s1 += __shfl_down(s1, off);
      s2 += __shfl_down(s2, off);
    }
    float* r1 = smemf;
    float* r2 = smemf + 4;
    float* sh = smemf + 8;
    if ((t & 63) == 0) { r1[t >> 6] = s1; r2[t >> 6] = s2; }
    __syncthreads();
    if (t == 0) {
      float t1 = r1[0] + r1[1] + r1[2] + r1[3];
      float t2 = r2[0] + r2[1] + r2[2] + r2[3];
      const float invN = 1.0f / 4096.0f;
      float mu  = t1 * invN;
      float var = t2 * invN - mu * mu;
      sh[0] = mu;
      sh[1] = rsqrtf(var + 1e-5f);
    }
    __syncthreads();
    const float mu = sh[0], rs = sh[1];
    for (int i = t; i < 1024; i += 256) {
      float4 v  = *(const float4*)(p + (size_t)i * 4);
      float4 gg = *(const float4*)(lng + (size_t)i * 4);
      float4 bb = *(const float4*)(lnb + (size_t)i * 4);
      bf16_t* o = enc + (size_t)row * 4096 + (size_t)i * 4;
      o[0] = (bf16_t)((v.x - mu) * rs * gg.x + bb.x);
      o[1] = (bf16_t)((v.y - mu) * rs * gg.y + bb.y);
      o[2] = (bf16_t)((v.z - mu) * rs * gg.z + bb.z);
      o[3] = (bf16_t)((v.w - mu) * rs * gg.w + bb.w);
    }
  }
}

// ---------------- merged gn_apply (finalize fused) + K/V split-K GEMM --------
// blocks [0,2560): gn_apply ; blocks [2560,3200): K/V proj (round-7 structure)
__global__ __launch_bounds__(256, 3) void k_gnapply_kv(
    const float* __restrict__ x, const float* __restrict__ partial,
    const float* __restrict__ gamma, const float* __restrict__ beta,
    bf16_t* __restrict__ h,
    const bf16_t* __restrict__ enc, const bf16_t* __restrict__ WkT,
    float* __restrict__ part)
{
  __shared__ alignas(16) char smraw[49152];
  const int bid = blockIdx.x;
  const int tid = threadIdx.x;

  if (bid < 2560) {
    // ---- GroupNorm apply + transpose ----
    float (*tile)[65] = (float(*)[65])smraw;
    float* sst = (float*)(smraw + 64 * 65 * sizeof(float));
    const int s0 = (bid & 63) * 64;
    const int c0 = ((bid >> 6) % 20) * 64;
    const int b  = bid / 1280;
    {
      const int g = tid >> 3, j = tid & 7;
      const int base = ((b * 32 + g) * 32) * 2;
      float s1 = 0.f, s2 = 0.f;
#pragma unroll
      for (int k = 0; k < 4; ++k) {
        s1 += partial[base + (j + 8 * k) * 2];
        s2 += partial[base + (j + 8 * k) * 2 + 1];
      }
      s1 += __shfl_down(s1, 1); s2 += __shfl_down(s2, 1);
      s1 += __shfl_down(s1, 2); s2 += __shfl_down(s2, 2);
      s1 += __shfl_down(s1, 4); s2 += __shfl_down(s2, 4);
      if (j == 0) {
        const float invN = 1.0f / 163840.0f;
        float mu  = s1 * invN;
        float var = s2 * invN - mu * mu;
        sst[g * 2]     = mu;
        sst[g * 2 + 1] = rsqrtf(var + 1e-5f);
      }
    }
#pragma unroll
    for (int it = 0; it < 16; ++it) {
      int cl = it * 4 + (tid >> 6);
      int sl = tid & 63;
      tile[cl][sl] = x[((size_t)(b * 1280 + c0 + cl) << 12) + s0 + sl];
    }
    __syncthreads();
#pragma unroll
    for (int it = 0; it < 2; ++it) {
      int i  = it * 256 + tid;
      int sl = i >> 3;
      int cg = i & 7;
      bf16x8 o;
#pragma unroll
      for (int e = 0; e < 8; ++e) {
        int c  = c0 + cg * 8 + e;
        int g  = c / 40;
        float mu = sst[g * 2];
        float rs = sst[g * 2 + 1];
        o[e] = (bf16_t)((tile[cg * 8 + e][sl] - mu) * rs * gamma[c] + beta[c]);
      }
      *(bf16x8*)(h + (size_t)(b * 4096 + s0 + sl) * 1280 + c0 + cg * 8) = o;
    }
    return;
  }

  // ---- K/V merged projection (split-K 8) ----
  bf16_t* smem = (bf16_t*)smraw;  // 48 KB
  const int lane = tid & 63;
  const int wv   = tid >> 6;
  const int wm   = wv >> 1, wn = wv & 1;
  const int xx   = bid - 2560;
  const int sk   = xx / 80;
  const int tl   = xx % 80;
  const int nb   = (tl & 7) * 10 + (tl >> 3);
  const int m0   = (nb / 40) * 128;
  const int n0   = (nb % 40) * 64;
  const int kbeg = sk * 512;
  const int lda  = 4096;

  f32x4 acc[4][2];
  const f32x4 fz = {0.f, 0.f, 0.f, 0.f};
#pragma unroll
  for (int i = 0; i < 4; ++i)
#pragma unroll
    for (int j = 0; j < 2; ++j) acc[i][j] = fz;

  auto stage = [&](int buf, int kt) {
    bf16_t* sA = smem + buf * 8192;
    bf16_t* sB = smem + 16384 + buf * 4096;
#pragma unroll
    for (int it = 0; it < 4; ++it) {
      int slot = it * 256 + tid;
      int row  = slot >> 3, ch = slot & 7;
      int grow = m0 + row; if (grow > 153) grow = 153;
      const bf16_t* ga = enc + (size_t)grow * lda + kt + ((ch ^ (row & 7)) << 3);
      __builtin_amdgcn_global_load_lds(
          (const __attribute__((address_space(1))) void*)ga,
          (__attribute__((address_space(3))) void*)((char*)sA + slot * 16),
          16, 0, 0);
    }
#pragma unroll
    for (int it = 0; it < 2; ++it) {
      int slot = it * 256 + tid;
      int row  = slot >> 3, ch = slot & 7;
      const bf16_t* gb = WkT + (size_t)(n0 + row) * lda + kt + ((ch ^ (row & 7)) << 3);
      __builtin_amdgcn_global_load_lds(
          (const __attribute__((address_space(1))) void*)gb,
          (__attribute__((address_space(3))) void*)((char*)sB + slot * 16),
          16, 0, 0);
    }
  };

  stage(0, kbeg);
  stage(1, kbeg + 64);

  for (int t = 0; t < 8; ++t) {
    if (t + 1 < 8) { asm volatile("s_waitcnt vmcnt(6)" ::: "memory"); }
    else           { asm volatile("s_waitcnt vmcnt(0)" ::: "memory"); }
    __builtin_amdgcn_s_barrier();
    const char* pA = (const char*)(smem + (t & 1) * 8192);
    const char* pB = (const char*)(smem + 16384 + (t & 1) * 4096);
#pragma unroll
    for (int ks = 0; ks < 2; ++ks) {
      const int kb = ks * 64 + ((lane >> 4) << 4);
      bf16x8 af[4], bfg[2];
#pragma unroll
      for (int i = 0; i < 4; ++i) {
        int r = wm * 64 + i * 16 + (lane & 15);
        af[i] = *(const bf16x8*)(pA + r * 128 + (kb ^ ((r & 7) << 4)));
      }
#pragma unroll
      for (int j = 0; j < 2; ++j) {
        int c = wn * 32 + j * 16 + (lane & 15);
        bfg[j] = *(const bf16x8*)(pB + c * 128 + (kb ^ ((c & 7) << 4)));
      }
#pragma unroll
      for (int i = 0; i < 4; ++i)
#pragma unroll
        for (int j = 0; j < 2; ++j)
          acc[i][j] = __builtin_amdgcn_mfma_f32_16x16x32_bf16(af[i], bfg[j], acc[i][j], 0, 0, 0);
    }
    asm volatile("s_waitcnt lgkmcnt(0)" ::: "memory");
    __builtin_amdgcn_s_barrier();
    if (t + 2 < 8) stage(t & 1, kbeg + (t + 2) * 64);
  }

#pragma unroll
  for (int i = 0; i < 4; ++i) {
    const int mrow = m0 + wm * 64 + i * 16 + ((lane >> 4) << 2);
#pragma unroll
    for (int j = 0; j < 2; ++j) {
      const int n = n0 + wn * 32 + j * 16 + (lane & 15);
#pragma unroll
      for (int r = 0; r < 4; ++r)
        if (mrow + r < 154)
          part[(size_t)sk * (154 * 2560) + (size_t)(mrow + r) * 2560 + n] = acc[i][j][r];
    }
  }
}

// ---------------- 256x256 8-phase-lite bf16 MFMA GEMM ------------------------
// 512 thr / 8 waves (2M x 4N), per-wave 128x64 (acc 8x4). BK=64, LDS 128 KB
// (A,B x 2 dbuf x 32 KB). Per K-tile: entry vmcnt(0)+barrier (queue holds ONLY
// tile t's 8 loads, issued a full tile earlier -> no stall, no over-drain);
// 4 phases of {ds_read quadrant -> barrier -> setprio+16 MFMA -> barrier};
// ALL of tile t+1's staging issues at phase 0 into the non-read buffer ->
// race-free by construction. Full-row (row&7) chunk swizzle (proven) applied
// on the GLOBAL source (linear LDS dest); ds_read applies the same swizzle.
// EPI 0 (+fused kv_reduce blocks >=160): outb bf16 = acc+bias via LDS staging
// EPI 2: dout fp32 = acc + bias + xres, (b,c,s) float4 store
template <int EPI>
__global__ __launch_bounds__(512, 1) void k_gemm256(
    const bf16_t* __restrict__ A, const bf16_t* __restrict__ BT,
    const float* __restrict__ bias, bf16_t* __restrict__ outb,
    const float* __restrict__ xres, float* __restrict__ dout,
    const float* __restrict__ part, const float* __restrict__ bk,
    const float* __restrict__ bv, bf16_t* __restrict__ kb, bf16_t* __restrict__ vb)
{
  __shared__ alignas(16) bf16_t smem[65536];  // 128 KB
  const int tid = threadIdx.x;

  if (EPI == 0 && blockIdx.x >= 160) {
    // ---- fused split-K reduce for K/V (float4) ----
    const int i4 = ((blockIdx.x - 160) * 512 + tid) * 4;
    if (i4 < 154 * 2560) {
      const int r = i4 / 2560, n = i4 % 2560;
      float4 s = (n < 1280) ? *(const float4*)(bk + n) : *(const float4*)(bv + n - 1280);
#pragma unroll
      for (int sp = 0; sp < 8; ++sp) {
        float4 p = *(const float4*)(part + (size_t)sp * (154 * 2560) + i4);
        s.x += p.x; s.y += p.y; s.z += p.z; s.w += p.w;
      }
      bf16_t* dst = (n < 1280) ? (kb + (size_t)r * 1280 + n)
                               : (vb + (size_t)r * 1280 + n - 1280);
      dst[0] = (bf16_t)s.x; dst[1] = (bf16_t)s.y;
      dst[2] = (bf16_t)s.z; dst[3] = (bf16_t)s.w;
    }
    return;
  }

  const int lane = tid & 63;
  const int wv   = tid >> 6;
  const int wm   = wv >> 2, wn = wv & 3;
  const int lda  = 1280;
  const int nt   = 20;

  const int nbid = (blockIdx.x & 7) * 20 + (blockIdx.x >> 3);  // 160 = 8*20
  const int m0   = (nbid / 5) * 256;
  const int n0   = (nbid % 5) * 256;

  f32x4 acc[8][4];
  const f32x4 fz = {0.f, 0.f, 0.f, 0.f};
#pragma unroll
  for (int i = 0; i < 8; ++i)
#pragma unroll
    for (int j = 0; j < 4; ++j) acc[i][j] = fz;

  // stage a FULL 256x64 A + 256x64 B tile (8 gload_lds/thread)
  auto stage_tile = [&](int buf, int kt) {
    bf16_t* sA = smem + buf * 16384;
    bf16_t* sB = smem + 32768 + buf * 16384;
#pragma unroll
    for (int it = 0; it < 4; ++it) {
      int slot = it * 512 + tid;
      int row = slot >> 3, ch = slot & 7;
      const bf16_t* ga = A + (size_t)(m0 + row) * lda + kt + ((ch ^ (row & 7)) << 3);
      __builtin_amdgcn_global_load_lds(
          (const __attribute__((address_space(1))) void*)ga,
          (__attribute__((address_space(3))) void*)((char*)sA + slot * 16),
          16, 0, 0);
    }
#pragma unroll
    for (int it = 0; it < 4; ++it) {
      int slot = it * 512 + tid;
      int row = slot >> 3, ch = slot & 7;
      const bf16_t* gb = BT + (size_t)(n0 + row) * lda + kt + ((ch ^ (row & 7)) << 3);
      __builtin_amdgcn_global_load_lds(
          (const __attribute__((address_space(1))) void*)gb,
          (__attribute__((address_space(3))) void*)((char*)sB + slot * 16),
          16, 0, 0);
    }
  };

  stage_tile(0, 0);

  for (int t = 0; t < nt; ++t) {
    asm volatile("s_waitcnt vmcnt(0)" ::: "memory");  // only tile t's loads queued
    __builtin_amdgcn_s_barrier();
    const char* pA = (const char*)(smem + (t & 1) * 16384);
    const char* pB = (const char*)(smem + 32768 + (t & 1) * 16384);
    bf16x8 bfg[4];
#pragma unroll
    for (int p = 0; p < 4; ++p) {
      const int mg = p & 1, ks = p >> 1;
      const int kb = ks * 64 + ((lane >> 4) << 4);
      bf16x8 af[4];
#pragma unroll
      for (int i = 0; i < 4; ++i) {
        int r = wm * 128 + (mg * 4 + i) * 16 + (lane & 15);
        af[i] = *(const bf16x8*)(pA + r * 128 + (kb ^ ((r & 7) << 4)));
      }
      if (mg == 0) {
#pragma unroll
        for (int j = 0; j < 4; ++j) {
          int c = wn * 64 + j * 16 + (lane & 15);
          bfg[j] = *(const bf16x8*)(pB + c * 128 + (kb ^ ((c & 7) << 4)));
        }
      }
      if (p == 0 && t + 1 < nt) stage_tile((t + 1) & 1, (t + 1) * 64);
      __builtin_amdgcn_s_barrier();
      __builtin_amdgcn_s_setprio(1);
#pragma unroll
      for (int i = 0; i < 4; ++i)
#pragma unroll
        for (int j = 0; j < 4; ++j)
          acc[mg * 4 + i][j] =
              __builtin_amdgcn_mfma_f32_16x16x32_bf16(af[i], bfg[j], acc[mg * 4 + i][j], 0, 0, 0);
      __builtin_amdgcn_s_setprio(0);
      __builtin_amdgcn_s_barrier();
    }
  }

  if (EPI == 0) {
    bf16_t* cst = smem;  // 128 x 264 bf16 per pass (67.6 KB)
    float bs[4];
#pragma unroll
    for (int j = 0; j < 4; ++j) bs[j] = bias[n0 + wn * 64 + j * 16 + (lane & 15)];
#pragma unroll
    for (int mh = 0; mh < 2; ++mh) {
      __syncthreads();
      if (wm == mh) {
#pragma unroll
        for (int fi = 0; fi < 8; ++fi) {
          const int rl = fi * 16 + ((lane >> 4) << 2);
#pragma unroll
          for (int j = 0; j < 4; ++j) {
            const int cl = wn * 64 + j * 16 + (lane & 15);
#pragma unroll
            for (int r = 0; r < 4; ++r)
              cst[(rl + r) * 264 + cl] = (bf16_t)(acc[fi][j][r] + bs[j]);
          }
        }
      }
      __syncthreads();
#pragma unroll
      for (int it = 0; it < 8; ++it) {
        int slot = it * 512 + tid;
        int row = slot >> 5, ch = slot & 31;
        u32x4 d = *(const u32x4*)(cst + row * 264 + ch * 8);
        *(u32x4*)(outb + (size_t)(m0 + mh * 128 + row) * 1280 + n0 + ch * 8) = d;
      }
    }
  } else {
#pragma unroll
    for (int fi = 0; fi < 8; ++fi) {
      const int mrow = m0 + wm * 128 + fi * 16 + ((lane >> 4) << 2);
      const int b = mrow >> 12, s = mrow & 4095;
#pragma unroll
      for (int j = 0; j < 4; ++j) {
        const int n = n0 + wn * 64 + j * 16 + (lane & 15);
        const size_t off = ((size_t)(b * 1280 + n) << 12) + s;
        const float bsv = bias[n];
        const float4 xr = *(const float4*)(xres + off);
        float4 o;
        o.x = acc[fi][j][0] + bsv + xr.x;
        o.y = acc[fi][j][1] + bsv + xr.y;
        o.z = acc[fi][j][2] + bsv + xr.z;
        o.w = acc[fi][j][3] + bsv + xr.w;
        *(float4*)(dout + off) = o;
      }
    }
  }
}

// ---------------- fused attention (per head, per 64-row s tile) ----------------
__global__ __launch_bounds__(256) void k_attn(
    const bf16_t* __restrict__ q, const bf16_t* __restrict__ kbuf,
    const bf16_t* __restrict__ vbuf, bf16_t* __restrict__ ao,
    const float* __restrict__ size_reg, const int* __restrict__ mask,
    const float* __restrict__ treg)
{
  __shared__ alignas(16) bf16_t sQ[64 * 64];
  __shared__ alignas(16) bf16_t sK[80 * 64];
  __shared__ alignas(16) bf16_t sVT[64 * 104];
  __shared__ alignas(16) bf16_t sP[4 * 16 * 104];
  const int s0   = blockIdx.x * 64;
  const int bh   = blockIdx.y;
  const int b    = bh / 20, head = bh % 20;
  const int tid  = threadIdx.x, lane = tid & 63, wv = tid >> 6;
  const int ntok = lane & 15;

  const u32x4 uz = {0u, 0u, 0u, 0u};
  for (int i = tid; i < 832; i += 256) ((u32x4*)sVT)[i] = uz;
  for (int i = tid; i < 832; i += 256) ((u32x4*)sP)[i]  = uz;

  const size_t qbase = ((size_t)(b * 4096 + s0)) * 1280 + head * 64;
  for (int slot = tid; slot < 512; slot += 256) {
    int row = slot >> 3, ch = slot & 7;
    u32x4 d = *(const u32x4*)(q + qbase + (size_t)row * 1280 + ((ch ^ (row & 7)) << 3));
    *(u32x4*)((char*)sQ + slot * 16) = d;
  }
  const size_t kvbase = ((size_t)(b * 77)) * 1280 + head * 64;
  for (int slot = tid; slot < 640; slot += 256) {
    int tok = slot >> 3, ch = slot & 7;
    u32x4 d = uz;
    if (tok < 77)
      d = *(const u32x4*)(kbuf + kvbase + (size_t)tok * 1280 + ((ch ^ (tok & 7)) << 3));
    *(u32x4*)((char*)sK + slot * 16) = d;
  }
  __syncthreads();
  for (int e = tid; e < 77 * 64; e += 256) {
    int tok = e >> 6, dh = e & 63;
    sVT[dh * 104 + tok] = vbuf[kvbase + (size_t)tok * 1280 + dh];
  }
  __syncthreads();

  f32x4 sim[5];
  const f32x4 fz = {0.f, 0.f, 0.f, 0.f};
#pragma unroll
  for (int nf = 0; nf < 5; ++nf) sim[nf] = fz;
  const int qrow = wv * 16 + (lane & 15);
#pragma unroll
  for (int ks = 0; ks < 2; ++ks) {
    const int kb = ks * 64 + ((lane >> 4) << 4);
    bf16x8 aq = *(const bf16x8*)((const char*)sQ + qrow * 128 + (kb ^ ((qrow & 7) << 4)));
#pragma unroll
    for (int nf = 0; nf < 5; ++nf) {
      int tok = nf * 16 + ntok;
      bf16x8 bk = *(const bf16x8*)((const char*)sK + tok * 128 + (kb ^ ((tok & 7) << 4)));
      sim[nf] = __builtin_amdgcn_mfma_f32_16x16x32_bf16(aq, bk, sim[nf], 0, 0, 0);
    }
  }

  float vv[5][4];
#pragma unroll
  for (int nf = 0; nf < 5; ++nf)
#pragma unroll
    for (int r = 0; r < 4; ++r) vv[nf][r] = sim[nf][r] * 0.125f;

  const int rbase = s0 + wv * 16 + ((lane >> 4) << 2);

  if (b == 1) {
    const float tr = treg[0];
#pragma unroll
    for (int r = 0; r < 4; ++r) {
      float mx = -1e30f, mn = 1e30f;
#pragma unroll
      for (int nf = 0; nf < 5; ++nf)
        if (nf * 16 + ntok < 77) { mx = fmaxf(mx, vv[nf][r]); mn = fminf(mn, vv[nf][r]); }
#pragma unroll
      for (int m = 1; m < 16; m <<= 1) {
        mx = fmaxf(mx, __shfl_xor(mx, m));
        mn = fminf(mn, __shfl_xor(mn, m));
      }
      const int srow = rbase + r;
#pragma unroll
      for (int nf = 0; nf < 5; ++nf) {
        int l = nf * 16 + ntok;
        if (l < 77) {
          float w  = size_reg[srow * 77 + l] * tr;
          int   mk = mask[srow * 77 + l];
          float v  = vv[nf][r];
          vv[nf][r] = (mk > 0) ? v + w * (mx - v) : v - w * (v - mn);
        }
      }
    }
  }

#pragma unroll
  for (int r = 0; r < 4; ++r) {
    float mx = -1e30f;
#pragma unroll
    for (int nf = 0; nf < 5; ++nf)
      if (nf * 16 + ntok < 77) mx = fmaxf(mx, vv[nf][r]);
#pragma unroll
    for (int m = 1; m < 16; m <<= 1) mx = fmaxf(mx, __shfl_xor(mx, m));
    float p[5]; float sm = 0.f;
#pragma unroll
    for (int nf = 0; nf < 5; ++nf) {
      bool val = (nf * 16 + ntok) < 77;
      p[nf] = val ? __expf(vv[nf][r] - mx) : 0.f;
      sm += p[nf];
    }
#pragma unroll
    for (int m = 1; m < 16; m <<= 1) sm += __shfl_xor(sm, m);
    const float inv = 1.0f / sm;
    const int prow = ((lane >> 4) << 2) + r;
#pragma unroll
    for (int nf = 0; nf < 5; ++nf)
      sP[wv * 1664 + prow * 104 + nf * 16 + ntok] = (bf16_t)(p[nf] * inv);
  }
  __syncthreads();

  f32x4 o[4];
#pragma unroll
  for (int fd = 0; fd < 4; ++fd) o[fd] = fz;
#pragma unroll
  for (int ks = 0; ks < 3; ++ks) {
    const int kb = ks * 64 + ((lane >> 4) << 4);
    bf16x8 ap = *(const bf16x8*)((const char*)sP + wv * 3328 + (lane & 15) * 208 + kb);
#pragma unroll
    for (int fd = 0; fd < 4; ++fd) {
      bf16x8 bv = *(const bf16x8*)((const char*)sVT + (fd * 16 + (lane & 15)) * 208 + kb);
      o[fd] = __builtin_amdgcn_mfma_f32_16x16x32_bf16(ap, bv, o[fd], 0, 0, 0);
    }
  }
  const size_t obase =
      ((size_t)(b * 4096 + s0 + wv * 16 + ((lane >> 4) << 2))) * 1280 + head * 64;
#pragma unroll
  for (int fd = 0; fd < 4; ++fd)
#pragma unroll
    for (int r = 0; r < 4; ++r)
      ao[obase + (size_t)r * 1280 + fd * 16 + (lane & 15)] = (bf16_t)o[fd][r];
}

// ---------------- host launch ----------------
extern "C" void kernel_launch(void* const* d_in, const int* in_sizes, int n_in,
                              void* d_out, int out_size, void* d_ws, size_t ws_size,
                              hipStream_t stream)
{
  const float* x    = (const float*)d_in[0];
  const float* text = (const float*)d_in[1];
  const float* gng  = (const float*)d_in[2];
  const float* gnb  = (const float*)d_in[3];
  const float* lng  = (const float*)d_in[4];
  const float* lnb  = (const float*)d_in[5];
  const float* Wq   = (const float*)d_in[6];
  const float* bq   = (const float*)d_in[7];
  const float* Wk   = (const float*)d_in[8];
  const float* bk   = (const float*)d_in[9];
  const float* Wv   = (const float*)d_in[10];
  const float* bv   = (const float*)d_in[11];
  const float* Wo   = (const float*)d_in[12];
  const float* bo   = (const float*)d_in[13];
  const float* sreg = (const float*)d_in[14];
  const float* treg = (const float*)d_in[15];
  const int*   msk  = (const int*)d_in[16];
  float* out = (float*)d_out;

  char* ws = (char*)d_ws;
  size_t off = 0;
  auto alloc = [&](size_t bytes) {
    char* p = ws + off;
    off += (bytes + 255) & ~(size_t)255;
    return p;
  };
  float*  partial = (float*)alloc(2048 * 2 * sizeof(float));
  bf16_t* WqT = (bf16_t*)alloc((size_t)1280 * 1280 * 2);
  bf16_t* WkT = (bf16_t*)alloc((size_t)1280 * 4096 * 2);  // WvT contiguous after
  bf16_t* WvT = (bf16_t*)alloc((size_t)1280 * 4096 * 2);
  bf16_t* WoT = (bf16_t*)alloc((size_t)1280 * 1280 * 2);
  bf16_t* h   = (bf16_t*)alloc((size_t)8192 * 1280 * 2);  // reused as attn_out
  bf16_t* enc = (bf16_t*)alloc((size_t)154 * 4096 * 2);
  bf16_t* qb  = (bf16_t*)alloc((size_t)8192 * 1280 * 2);
  bf16_t* kb  = (bf16_t*)alloc((size_t)154 * 1280 * 2);
  bf16_t* vb  = (bf16_t*)alloc((size_t)154 * 1280 * 2);
  float*  part = (float*)alloc((size_t)8 * 154 * 2560 * sizeof(float));

  // 1) prep: 4 weight transposes + gn_partial + layernorm
  k_prep<<<8922, 256, 0, stream>>>(x, text, lng, lnb, Wq, Wo, Wk, Wv,
                                   WqT, WoT, WkT, WvT, partial, enc);

  // 2) gn apply (finalize fused) + K/V split-K GEMM in one launch
  k_gnapply_kv<<<3200, 256, 0, stream>>>(x, partial, gng, gnb, h, enc, WkT, part);

  // 3) Q projection (256x256 8-phase-lite, 160 blocks) + fused kv_reduce (193)
  k_gemm256<0><<<353, 512, 0, stream>>>(h, WqT, bq, qb, nullptr, nullptr,
                                        part, bk, bv, kb, vb);

  // 4) attention (writes attn_out into h buffer)
  k_attn<<<dim3(64, 40), 256, 0, stream>>>(qb, kb, vb, h, sreg, msk, treg);

  // 5) output projection + residual + transpose to (B,C,S)
  k_gemm256<2><<<160, 512, 0, stream>>>(h, WoT, bo, nullptr, x, out,
                                        nullptr, nullptr, nullptr, nullptr, nullptr);
}

// Round 16
// 159.436 us; speedup vs baseline: 1.1347x; 1.1347x over previous
//
#include <hip/hip_runtime.h>

typedef __bf16 bf16_t;
typedef __bf16 bf16x8 __attribute__((ext_vector_type(8)));
typedef float  f32x4  __attribute__((ext_vector_type(4)));
typedef unsigned int u32x4 __attribute__((ext_vector_type(4)));

// problem constants
// B=2 C=1280 HEADS=20 DH=64 S=4096 L=77 ENC=4096 GROUPS=32 EPS=1e-5

// ---------------- fat prep kernel: 4 transposes + gn_partial + layernorm -----
__global__ __launch_bounds__(256) void k_prep(
    const float* __restrict__ x, const float* __restrict__ text,
    const float* __restrict__ lng, const float* __restrict__ lnb,
    const float* __restrict__ w0, const float* __restrict__ w1,
    const float* __restrict__ w2, const float* __restrict__ w3,
    bf16_t* __restrict__ o0, bf16_t* __restrict__ o1,
    bf16_t* __restrict__ o2, bf16_t* __restrict__ o3,
    float* __restrict__ partial, bf16_t* __restrict__ enc)
{
  __shared__ float smemf[64 * 33];
  const int bid = blockIdx.x;
  const int t   = threadIdx.x;

  if (bid < 6720) {
    int z, lb;
    if      (bid < 800)  { z = 0; lb = bid; }
    else if (bid < 1600) { z = 1; lb = bid - 800; }
    else if (bid < 4160) { z = 2; lb = bid - 1600; }
    else                 { z = 3; lb = bid - 4160; }
    const float* in  = (z == 0) ? w0 : (z == 1) ? w1 : (z == 2) ? w2 : w3;
    bf16_t*      out = (z == 0) ? o0 : (z == 1) ? o1 : (z == 2) ? o2 : o3;
    const int R  = (z < 2) ? 1280 : 4096;
    const int c0 = (lb % 40) * 32;
    const int r0 = (lb / 40) * 64;
    float (*tile)[33] = (float(*)[33])smemf;
#pragma unroll
    for (int it = 0; it < 8; ++it) {
      int r = it * 8 + (t >> 5), c = t & 31;
      tile[r][c] = in[(size_t)(r0 + r) * 1280 + c0 + c];
    }
    __syncthreads();
    const int oc  = t >> 3;
    const int seg = t & 7;
    bf16x8 o;
#pragma unroll
    for (int e = 0; e < 8; ++e) o[e] = (bf16_t)tile[seg * 8 + e][oc];
    *(bf16x8*)(out + (size_t)(c0 + oc) * R + r0 + seg * 8) = o;
  } else if (bid < 8768) {
    const int pb    = bid - 6720;
    const int bg    = pb >> 5;
    const int chunk = pb & 31;
    const float* p  = x + (size_t)bg * 163840 + (size_t)chunk * 5120;
    float s1 = 0.f, s2 = 0.f;
#pragma unroll
    for (int it = 0; it < 5; ++it) {
      float4 v = *(const float4*)(p + (size_t)(it * 256 + t) * 4);
      s1 += v.x + v.y + v.z + v.w;
      s2 += v.x * v.x + v.y * v.y + v.z * v.z + v.w * v.w;
    }
#pragma unroll
    for (int off = 32; off > 0; off >>= 1) {
      s1 += __shfl_down(s1, off);
      s2 += __shfl_down(s2, off);
    }
    float* r1 = smemf;
    float* r2 = smemf + 4;
    if ((t & 63) == 0) { r1[t >> 6] = s1; r2[t >> 6] = s2; }
    __syncthreads();
    if (t == 0) {
      partial[pb * 2]     = r1[0] + r1[1] + r1[2] + r1[3];
      partial[pb * 2 + 1] = r2[0] + r2[1] + r2[2] + r2[3];
    }
  } else {
    const int row = bid - 8768;
    const float* p = text + (size_t)row * 4096;
    float s1 = 0.f, s2 = 0.f;
    for (int i = t; i < 1024; i += 256) {
      float4 v = *(const float4*)(p + (size_t)i * 4);
      s1 += v.x + v.y + v.z + v.w;
      s2 += v.x * v.x + v.y * v.y + v.z * v.z + v.w * v.w;
    }
#pragma unroll
    for (int off = 32; off > 0; off >>= 1) {
      s1 += __shfl_down(s1, off);
      s2 += __shfl_down(s2, off);
    }
    float* r1 = smemf;
    float* r2 = smemf + 4;
    float* sh = smemf + 8;
    if ((t & 63) == 0) { r1[t >> 6] = s1; r2[t >> 6] = s2; }
    __syncthreads();
    if (t == 0) {
      float t1 = r1[0] + r1[1] + r1[2] + r1[3];
      float t2 = r2[0] + r2[1] + r2[2] + r2[3];
      const float invN = 1.0f / 4096.0f;
      float mu  = t1 * invN;
      float var = t2 * invN - mu * mu;
      sh[0] = mu;
      sh[1] = rsqrtf(var + 1e-5f);
    }
    __syncthreads();
    const float mu = sh[0], rs = sh[1];
    for (int i = t; i < 1024; i += 256) {
      float4 v  = *(const float4*)(p + (size_t)i * 4);
      float4 gg = *(const float4*)(lng + (size_t)i * 4);
      float4 bb = *(const float4*)(lnb + (size_t)i * 4);
      bf16_t* o = enc + (size_t)row * 4096 + (size_t)i * 4;
      o[0] = (bf16_t)((v.x - mu) * rs * gg.x + bb.x);
      o[1] = (bf16_t)((v.y - mu) * rs * gg.y + bb.y);
      o[2] = (bf16_t)((v.z - mu) * rs * gg.z + bb.z);
      o[3] = (bf16_t)((v.w - mu) * rs * gg.w + bb.w);
    }
  }
}

// ---------------- merged gn_apply (finalize fused) + K/V split-K GEMM --------
// blocks [0,2560): gn_apply ; blocks [2560,3200): K/V proj (round-7 structure)
__global__ __launch_bounds__(256, 3) void k_gnapply_kv(
    const float* __restrict__ x, const float* __restrict__ partial,
    const float* __restrict__ gamma, const float* __restrict__ beta,
    bf16_t* __restrict__ h,
    const bf16_t* __restrict__ enc, const bf16_t* __restrict__ WkT,
    float* __restrict__ part)
{
  __shared__ alignas(16) char smraw[49152];
  const int bid = blockIdx.x;
  const int tid = threadIdx.x;

  if (bid < 2560) {
    float (*tile)[65] = (float(*)[65])smraw;
    float* sst = (float*)(smraw + 64 * 65 * sizeof(float));
    const int s0 = (bid & 63) * 64;
    const int c0 = ((bid >> 6) % 20) * 64;
    const int b  = bid / 1280;
    {
      const int g = tid >> 3, j = tid & 7;
      const int base = ((b * 32 + g) * 32) * 2;
      float s1 = 0.f, s2 = 0.f;
#pragma unroll
      for (int k = 0; k < 4; ++k) {
        s1 += partial[base + (j + 8 * k) * 2];
        s2 += partial[base + (j + 8 * k) * 2 + 1];
      }
      s1 += __shfl_down(s1, 1); s2 += __shfl_down(s2, 1);
      s1 += __shfl_down(s1, 2); s2 += __shfl_down(s2, 2);
      s1 += __shfl_down(s1, 4); s2 += __shfl_down(s2, 4);
      if (j == 0) {
        const float invN = 1.0f / 163840.0f;
        float mu  = s1 * invN;
        float var = s2 * invN - mu * mu;
        sst[g * 2]     = mu;
        sst[g * 2 + 1] = rsqrtf(var + 1e-5f);
      }
    }
#pragma unroll
    for (int it = 0; it < 16; ++it) {
      int cl = it * 4 + (tid >> 6);
      int sl = tid & 63;
      tile[cl][sl] = x[((size_t)(b * 1280 + c0 + cl) << 12) + s0 + sl];
    }
    __syncthreads();
#pragma unroll
    for (int it = 0; it < 2; ++it) {
      int i  = it * 256 + tid;
      int sl = i >> 3;
      int cg = i & 7;
      bf16x8 o;
#pragma unroll
      for (int e = 0; e < 8; ++e) {
        int c  = c0 + cg * 8 + e;
        int g  = c / 40;
        float mu = sst[g * 2];
        float rs = sst[g * 2 + 1];
        o[e] = (bf16_t)((tile[cg * 8 + e][sl] - mu) * rs * gamma[c] + beta[c]);
      }
      *(bf16x8*)(h + (size_t)(b * 4096 + s0 + sl) * 1280 + c0 + cg * 8) = o;
    }
    return;
  }

  bf16_t* smem = (bf16_t*)smraw;  // 48 KB
  const int lane = tid & 63;
  const int wv   = tid >> 6;
  const int wm   = wv >> 1, wn = wv & 1;
  const int xx   = bid - 2560;
  const int sk   = xx / 80;
  const int tl   = xx % 80;
  const int nb   = (tl & 7) * 10 + (tl >> 3);
  const int m0   = (nb / 40) * 128;
  const int n0   = (nb % 40) * 64;
  const int kbeg = sk * 512;
  const int lda  = 4096;

  f32x4 acc[4][2];
  const f32x4 fz = {0.f, 0.f, 0.f, 0.f};
#pragma unroll
  for (int i = 0; i < 4; ++i)
#pragma unroll
    for (int j = 0; j < 2; ++j) acc[i][j] = fz;

  auto stage = [&](int buf, int kt) {
    bf16_t* sA = smem + buf * 8192;
    bf16_t* sB = smem + 16384 + buf * 4096;
#pragma unroll
    for (int it = 0; it < 4; ++it) {
      int slot = it * 256 + tid;
      int row  = slot >> 3, ch = slot & 7;
      int grow = m0 + row; if (grow > 153) grow = 153;
      const bf16_t* ga = enc + (size_t)grow * lda + kt + ((ch ^ (row & 7)) << 3);
      __builtin_amdgcn_global_load_lds(
          (const __attribute__((address_space(1))) void*)ga,
          (__attribute__((address_space(3))) void*)((char*)sA + slot * 16),
          16, 0, 0);
    }
#pragma unroll
    for (int it = 0; it < 2; ++it) {
      int slot = it * 256 + tid;
      int row  = slot >> 3, ch = slot & 7;
      const bf16_t* gb = WkT + (size_t)(n0 + row) * lda + kt + ((ch ^ (row & 7)) << 3);
      __builtin_amdgcn_global_load_lds(
          (const __attribute__((address_space(1))) void*)gb,
          (__attribute__((address_space(3))) void*)((char*)sB + slot * 16),
          16, 0, 0);
    }
  };

  stage(0, kbeg);
  stage(1, kbeg + 64);

  for (int t = 0; t < 8; ++t) {
    if (t + 1 < 8) { asm volatile("s_waitcnt vmcnt(6)" ::: "memory"); }
    else           { asm volatile("s_waitcnt vmcnt(0)" ::: "memory"); }
    __builtin_amdgcn_s_barrier();
    const char* pA = (const char*)(smem + (t & 1) * 8192);
    const char* pB = (const char*)(smem + 16384 + (t & 1) * 4096);
#pragma unroll
    for (int ks = 0; ks < 2; ++ks) {
      const int kb = ks * 64 + ((lane >> 4) << 4);
      bf16x8 af[4], bfg[2];
#pragma unroll
      for (int i = 0; i < 4; ++i) {
        int r = wm * 64 + i * 16 + (lane & 15);
        af[i] = *(const bf16x8*)(pA + r * 128 + (kb ^ ((r & 7) << 4)));
      }
#pragma unroll
      for (int j = 0; j < 2; ++j) {
        int c = wn * 32 + j * 16 + (lane & 15);
        bfg[j] = *(const bf16x8*)(pB + c * 128 + (kb ^ ((c & 7) << 4)));
      }
#pragma unroll
      for (int i = 0; i < 4; ++i)
#pragma unroll
        for (int j = 0; j < 2; ++j)
          acc[i][j] = __builtin_amdgcn_mfma_f32_16x16x32_bf16(af[i], bfg[j], acc[i][j], 0, 0, 0);
    }
    asm volatile("s_waitcnt lgkmcnt(0)" ::: "memory");
    __builtin_amdgcn_s_barrier();
    if (t + 2 < 8) stage(t & 1, kbeg + (t + 2) * 64);
  }

#pragma unroll
  for (int i = 0; i < 4; ++i) {
    const int mrow = m0 + wm * 64 + i * 16 + ((lane >> 4) << 2);
#pragma unroll
    for (int j = 0; j < 2; ++j) {
      const int n = n0 + wn * 32 + j * 16 + (lane & 15);
#pragma unroll
      for (int r = 0; r < 4; ++r)
        if (mrow + r < 154)
          part[(size_t)sk * (154 * 2560) + (size_t)(mrow + r) * 2560 + n] = acc[i][j][r];
    }
  }
}

// ---------------- Q projection (round-7 proven) + fused kv_reduce tail -------
// blocks [0,1280): Q-proj 128x64, XCD-chunk swizzle; [1280,1665): kv_reduce
__global__ __launch_bounds__(256, 3) void k_gemm_q(
    const bf16_t* __restrict__ A, const bf16_t* __restrict__ BT,
    const float* __restrict__ bias, bf16_t* __restrict__ outb,
    const float* __restrict__ part, const float* __restrict__ bk,
    const float* __restrict__ bv, bf16_t* __restrict__ kb, bf16_t* __restrict__ vb)
{
  __shared__ alignas(16) bf16_t smem[24576];  // 48 KB
  const int tid = threadIdx.x;

  if (blockIdx.x >= 1280) {
    // ---- fused split-K reduce for K/V (float4) ----
    const int i4 = ((blockIdx.x - 1280) * 256 + tid) * 4;
    if (i4 < 154 * 2560) {
      const int r = i4 / 2560, n = i4 % 2560;
      float4 s = (n < 1280) ? *(const float4*)(bk + n) : *(const float4*)(bv + n - 1280);
#pragma unroll
      for (int sp = 0; sp < 8; ++sp) {
        float4 p = *(const float4*)(part + (size_t)sp * (154 * 2560) + i4);
        s.x += p.x; s.y += p.y; s.z += p.z; s.w += p.w;
      }
      bf16_t* dst = (n < 1280) ? (kb + (size_t)r * 1280 + n)
                               : (vb + (size_t)r * 1280 + n - 1280);
      dst[0] = (bf16_t)s.x; dst[1] = (bf16_t)s.y;
      dst[2] = (bf16_t)s.z; dst[3] = (bf16_t)s.w;
    }
    return;
  }

  const int lane = tid & 63;
  const int wv   = tid >> 6;
  const int wm   = wv >> 1, wn = wv & 1;
  const int nbid = (blockIdx.x & 7) * 160 + (blockIdx.x >> 3);
  const int m0   = (nbid / 20) * 128;
  const int n0   = (nbid % 20) * 64;
  const int lda  = 1280;

  f32x4 acc[4][2];
  const f32x4 fz = {0.f, 0.f, 0.f, 0.f};
#pragma unroll
  for (int i = 0; i < 4; ++i)
#pragma unroll
    for (int j = 0; j < 2; ++j) acc[i][j] = fz;

  auto stage = [&](int buf, int kt) {
    bf16_t* sA = smem + buf * 8192;
    bf16_t* sB = smem + 16384 + buf * 4096;
#pragma unroll
    for (int it = 0; it < 4; ++it) {
      int slot = it * 256 + tid;
      int row  = slot >> 3, ch = slot & 7;
      const bf16_t* ga = A + (size_t)(m0 + row) * lda + kt + ((ch ^ (row & 7)) << 3);
      __builtin_amdgcn_global_load_lds(
          (const __attribute__((address_space(1))) void*)ga,
          (__attribute__((address_space(3))) void*)((char*)sA + slot * 16),
          16, 0, 0);
    }
#pragma unroll
    for (int it = 0; it < 2; ++it) {
      int slot = it * 256 + tid;
      int row  = slot >> 3, ch = slot & 7;
      const bf16_t* gb = BT + (size_t)(n0 + row) * lda + kt + ((ch ^ (row & 7)) << 3);
      __builtin_amdgcn_global_load_lds(
          (const __attribute__((address_space(1))) void*)gb,
          (__attribute__((address_space(3))) void*)((char*)sB + slot * 16),
          16, 0, 0);
    }
  };

  const int nt_k = 20;
  stage(0, 0);
  stage(1, 64);

  for (int t = 0; t < nt_k; ++t) {
    if (t + 1 < nt_k) { asm volatile("s_waitcnt vmcnt(6)" ::: "memory"); }
    else              { asm volatile("s_waitcnt vmcnt(0)" ::: "memory"); }
    __builtin_amdgcn_s_barrier();
    const char* pA = (const char*)(smem + (t & 1) * 8192);
    const char* pB = (const char*)(smem + 16384 + (t & 1) * 4096);
#pragma unroll
    for (int ks = 0; ks < 2; ++ks) {
      const int kb = ks * 64 + ((lane >> 4) << 4);
      bf16x8 af[4], bfg[2];
#pragma unroll
      for (int i = 0; i < 4; ++i) {
        int r = wm * 64 + i * 16 + (lane & 15);
        af[i] = *(const bf16x8*)(pA + r * 128 + (kb ^ ((r & 7) << 4)));
      }
#pragma unroll
      for (int j = 0; j < 2; ++j) {
        int c = wn * 32 + j * 16 + (lane & 15);
        bfg[j] = *(const bf16x8*)(pB + c * 128 + (kb ^ ((c & 7) << 4)));
      }
#pragma unroll
      for (int i = 0; i < 4; ++i)
#pragma unroll
        for (int j = 0; j < 2; ++j)
          acc[i][j] = __builtin_amdgcn_mfma_f32_16x16x32_bf16(af[i], bfg[j], acc[i][j], 0, 0, 0);
    }
    asm volatile("s_waitcnt lgkmcnt(0)" ::: "memory");
    __builtin_amdgcn_s_barrier();
    if (t + 2 < nt_k) stage(t & 1, (t + 2) * 64);
  }

  bf16_t* cst = smem;  // 128 x 76 bf16
#pragma unroll
  for (int j = 0; j < 2; ++j) {
    const int n  = n0 + wn * 32 + j * 16 + (lane & 15);
    const float bs = bias[n];
    const int cl = wn * 32 + j * 16 + (lane & 15);
#pragma unroll
    for (int i = 0; i < 4; ++i) {
      const int rl = wm * 64 + i * 16 + ((lane >> 4) << 2);
#pragma unroll
      for (int r = 0; r < 4; ++r)
        cst[(rl + r) * 76 + cl] = (bf16_t)(acc[i][j][r] + bs);
    }
  }
  __syncthreads();
#pragma unroll
  for (int it = 0; it < 4; ++it) {
    int slot = it * 256 + tid;
    int row = slot >> 3, ch = slot & 7;
    u32x4 d = *(const u32x4*)(cst + row * 76 + ch * 8);
    *(u32x4*)(outb + (size_t)(m0 + row) * 1280 + n0 + ch * 8) = d;
  }
}

// ---------------- O-proj GEMM (round-7/12 proven, EPI2) ----------------------
__global__ __launch_bounds__(256, 3) void k_gemm_o(
    const bf16_t* __restrict__ A, const bf16_t* __restrict__ BT,
    const float* __restrict__ bias, const float* __restrict__ xres,
    float* __restrict__ dout)
{
  __shared__ alignas(16) bf16_t smem[24576];
  const int tid  = threadIdx.x;
  const int lane = tid & 63;
  const int wv   = tid >> 6;
  const int wm   = wv >> 1, wn = wv & 1;

  const int nbid = (blockIdx.x & 7) * 160 + (blockIdx.x >> 3);
  const int m0   = (nbid / 20) * 128;
  const int n0   = (nbid % 20) * 64;
  const int lda  = 1280;

  f32x4 acc[4][2];
  const f32x4 fz = {0.f, 0.f, 0.f, 0.f};
#pragma unroll
  for (int i = 0; i < 4; ++i)
#pragma unroll
    for (int j = 0; j < 2; ++j) acc[i][j] = fz;

  auto stage = [&](int buf, int kt) {
    bf16_t* sA = smem + buf * 8192;
    bf16_t* sB = smem + 16384 + buf * 4096;
#pragma unroll
    for (int it = 0; it < 4; ++it) {
      int slot = it * 256 + tid;
      int row  = slot >> 3, ch = slot & 7;
      const bf16_t* ga = A + (size_t)(m0 + row) * lda + kt + ((ch ^ (row & 7)) << 3);
      __builtin_amdgcn_global_load_lds(
          (const __attribute__((address_space(1))) void*)ga,
          (__attribute__((address_space(3))) void*)((char*)sA + slot * 16),
          16, 0, 0);
    }
#pragma unroll
    for (int it = 0; it < 2; ++it) {
      int slot = it * 256 + tid;
      int row  = slot >> 3, ch = slot & 7;
      const bf16_t* gb = BT + (size_t)(n0 + row) * lda + kt + ((ch ^ (row & 7)) << 3);
      __builtin_amdgcn_global_load_lds(
          (const __attribute__((address_space(1))) void*)gb,
          (__attribute__((address_space(3))) void*)((char*)sB + slot * 16),
          16, 0, 0);
    }
  };

  const int nt_k = 20;
  stage(0, 0);
  stage(1, 64);

  for (int t = 0; t < nt_k; ++t) {
    if (t + 1 < nt_k) { asm volatile("s_waitcnt vmcnt(6)" ::: "memory"); }
    else              { asm volatile("s_waitcnt vmcnt(0)" ::: "memory"); }
    __builtin_amdgcn_s_barrier();
    const char* pA = (const char*)(smem + (t & 1) * 8192);
    const char* pB = (const char*)(smem + 16384 + (t & 1) * 4096);
#pragma unroll
    for (int ks = 0; ks < 2; ++ks) {
      const int kb = ks * 64 + ((lane >> 4) << 4);
      bf16x8 af[4], bfg[2];
#pragma unroll
      for (int i = 0; i < 4; ++i) {
        int r = wm * 64 + i * 16 + (lane & 15);
        af[i] = *(const bf16x8*)(pA + r * 128 + (kb ^ ((r & 7) << 4)));
      }
#pragma unroll
      for (int j = 0; j < 2; ++j) {
        int c = wn * 32 + j * 16 + (lane & 15);
        bfg[j] = *(const bf16x8*)(pB + c * 128 + (kb ^ ((c & 7) << 4)));
      }
#pragma unroll
      for (int i = 0; i < 4; ++i)
#pragma unroll
        for (int j = 0; j < 2; ++j)
          acc[i][j] = __builtin_amdgcn_mfma_f32_16x16x32_bf16(af[i], bfg[j], acc[i][j], 0, 0, 0);
    }
    asm volatile("s_waitcnt lgkmcnt(0)" ::: "memory");
    __builtin_amdgcn_s_barrier();
    if (t + 2 < nt_k) stage(t & 1, (t + 2) * 64);
  }

#pragma unroll
  for (int i = 0; i < 4; ++i) {
    const int mrow = m0 + wm * 64 + i * 16 + ((lane >> 4) << 2);
    const int b = mrow >> 12, s = mrow & 4095;
#pragma unroll
    for (int j = 0; j < 2; ++j) {
      const int n = n0 + wn * 32 + j * 16 + (lane & 15);
      const size_t off = ((size_t)(b * 1280 + n) << 12) + s;
      const float bs = bias[n];
      const float4 xr = *(const float4*)(xres + off);
      float4 o;
      o.x = acc[i][j][0] + bs + xr.x;
      o.y = acc[i][j][1] + bs + xr.y;
      o.z = acc[i][j][2] + bs + xr.z;
      o.w = acc[i][j][3] + bs + xr.w;
      *(float4*)(dout + off) = o;
    }
  }
}

// ---------------- fused attention (per head, per 64-row s tile) ----------------
__global__ __launch_bounds__(256) void k_attn(
    const bf16_t* __restrict__ q, const bf16_t* __restrict__ kbuf,
    const bf16_t* __restrict__ vbuf, bf16_t* __restrict__ ao,
    const float* __restrict__ size_reg, const int* __restrict__ mask,
    const float* __restrict__ treg)
{
  __shared__ alignas(16) bf16_t sQ[64 * 64];
  __shared__ alignas(16) bf16_t sK[80 * 64];
  __shared__ alignas(16) bf16_t sVT[64 * 104];
  __shared__ alignas(16) bf16_t sP[4 * 16 * 104];
  const int s0   = blockIdx.x * 64;
  const int bh   = blockIdx.y;
  const int b    = bh / 20, head = bh % 20;
  const int tid  = threadIdx.x, lane = tid & 63, wv = tid >> 6;
  const int ntok = lane & 15;

  const u32x4 uz = {0u, 0u, 0u, 0u};
  for (int i = tid; i < 832; i += 256) ((u32x4*)sVT)[i] = uz;
  for (int i = tid; i < 832; i += 256) ((u32x4*)sP)[i]  = uz;

  const size_t qbase = ((size_t)(b * 4096 + s0)) * 1280 + head * 64;
  for (int slot = tid; slot < 512; slot += 256) {
    int row = slot >> 3, ch = slot & 7;
    u32x4 d = *(const u32x4*)(q + qbase + (size_t)row * 1280 + ((ch ^ (row & 7)) << 3));
    *(u32x4*)((char*)sQ + slot * 16) = d;
  }
  const size_t kvbase = ((size_t)(b * 77)) * 1280 + head * 64;
  for (int slot = tid; slot < 640; slot += 256) {
    int tok = slot >> 3, ch = slot & 7;
    u32x4 d = uz;
    if (tok < 77)
      d = *(const u32x4*)(kbuf + kvbase + (size_t)tok * 1280 + ((ch ^ (tok & 7)) << 3));
    *(u32x4*)((char*)sK + slot * 16) = d;
  }
  __syncthreads();
  for (int e = tid; e < 77 * 64; e += 256) {
    int tok = e >> 6, dh = e & 63;
    sVT[dh * 104 + tok] = vbuf[kvbase + (size_t)tok * 1280 + dh];
  }
  __syncthreads();

  f32x4 sim[5];
  const f32x4 fz = {0.f, 0.f, 0.f, 0.f};
#pragma unroll
  for (int nf = 0; nf < 5; ++nf) sim[nf] = fz;
  const int qrow = wv * 16 + (lane & 15);
#pragma unroll
  for (int ks = 0; ks < 2; ++ks) {
    const int kb = ks * 64 + ((lane >> 4) << 4);
    bf16x8 aq = *(const bf16x8*)((const char*)sQ + qrow * 128 + (kb ^ ((qrow & 7) << 4)));
#pragma unroll
    for (int nf = 0; nf < 5; ++nf) {
      int tok = nf * 16 + ntok;
      bf16x8 bk = *(const bf16x8*)((const char*)sK + tok * 128 + (kb ^ ((tok & 7) << 4)));
      sim[nf] = __builtin_amdgcn_mfma_f32_16x16x32_bf16(aq, bk, sim[nf], 0, 0, 0);
    }
  }

  float vv[5][4];
#pragma unroll
  for (int nf = 0; nf < 5; ++nf)
#pragma unroll
    for (int r = 0; r < 4; ++r) vv[nf][r] = sim[nf][r] * 0.125f;

  const int rbase = s0 + wv * 16 + ((lane >> 4) << 2);

  if (b == 1) {
    const float tr = treg[0];
#pragma unroll
    for (int r = 0; r < 4; ++r) {
      float mx = -1e30f, mn = 1e30f;
#pragma unroll
      for (int nf = 0; nf < 5; ++nf)
        if (nf * 16 + ntok < 77) { mx = fmaxf(mx, vv[nf][r]); mn = fminf(mn, vv[nf][r]); }
#pragma unroll
      for (int m = 1; m < 16; m <<= 1) {
        mx = fmaxf(mx, __shfl_xor(mx, m));
        mn = fminf(mn, __shfl_xor(mn, m));
      }
      const int srow = rbase + r;
#pragma unroll
      for (int nf = 0; nf < 5; ++nf) {
        int l = nf * 16 + ntok;
        if (l < 77) {
          float w  = size_reg[srow * 77 + l] * tr;
          int   mk = mask[srow * 77 + l];
          float v  = vv[nf][r];
          vv[nf][r] = (mk > 0) ? v + w * (mx - v) : v - w * (v - mn);
        }
      }
    }
  }

#pragma unroll
  for (int r = 0; r < 4; ++r) {
    float mx = -1e30f;
#pragma unroll
    for (int nf = 0; nf < 5; ++nf)
      if (nf * 16 + ntok < 77) mx = fmaxf(mx, vv[nf][r]);
#pragma unroll
    for (int m = 1; m < 16; m <<= 1) mx = fmaxf(mx, __shfl_xor(mx, m));
    float p[5]; float sm = 0.f;
#pragma unroll
    for (int nf = 0; nf < 5; ++nf) {
      bool val = (nf * 16 + ntok) < 77;
      p[nf] = val ? __expf(vv[nf][r] - mx) : 0.f;
      sm += p[nf];
    }
#pragma unroll
    for (int m = 1; m < 16; m <<= 1) sm += __shfl_xor(sm, m);
    const float inv = 1.0f / sm;
    const int prow = ((lane >> 4) << 2) + r;
#pragma unroll
    for (int nf = 0; nf < 5; ++nf)
      sP[wv * 1664 + prow * 104 + nf * 16 + ntok] = (bf16_t)(p[nf] * inv);
  }
  __syncthreads();

  f32x4 o[4];
#pragma unroll
  for (int fd = 0; fd < 4; ++fd) o[fd] = fz;
#pragma unroll
  for (int ks = 0; ks < 3; ++ks) {
    const int kb = ks * 64 + ((lane >> 4) << 4);
    bf16x8 ap = *(const bf16x8*)((const char*)sP + wv * 3328 + (lane & 15) * 208 + kb);
#pragma unroll
    for (int fd = 0; fd < 4; ++fd) {
      bf16x8 bv = *(const bf16x8*)((const char*)sVT + (fd * 16 + (lane & 15)) * 208 + kb);
      o[fd] = __builtin_amdgcn_mfma_f32_16x16x32_bf16(ap, bv, o[fd], 0, 0, 0);
    }
  }
  const size_t obase =
      ((size_t)(b * 4096 + s0 + wv * 16 + ((lane >> 4) << 2))) * 1280 + head * 64;
#pragma unroll
  for (int fd = 0; fd < 4; ++fd)
#pragma unroll
    for (int r = 0; r < 4; ++r)
      ao[obase + (size_t)r * 1280 + fd * 16 + (lane & 15)] = (bf16_t)o[fd][r];
}

// ---------------- host launch ----------------
extern "C" void kernel_launch(void* const* d_in, const int* in_sizes, int n_in,
                              void* d_out, int out_size, void* d_ws, size_t ws_size,
                              hipStream_t stream)
{
  const float* x    = (const float*)d_in[0];
  const float* text = (const float*)d_in[1];
  const float* gng  = (const float*)d_in[2];
  const float* gnb  = (const float*)d_in[3];
  const float* lng  = (const float*)d_in[4];
  const float* lnb  = (const float*)d_in[5];
  const float* Wq   = (const float*)d_in[6];
  const float* bq   = (const float*)d_in[7];
  const float* Wk   = (const float*)d_in[8];
  const float* bk   = (const float*)d_in[9];
  const float* Wv   = (const float*)d_in[10];
  const float* bv   = (const float*)d_in[11];
  const float* Wo   = (const float*)d_in[12];
  const float* bo   = (const float*)d_in[13];
  const float* sreg = (const float*)d_in[14];
  const float* treg = (const float*)d_in[15];
  const int*   msk  = (const int*)d_in[16];
  float* out = (float*)d_out;

  char* ws = (char*)d_ws;
  size_t off = 0;
  auto alloc = [&](size_t bytes) {
    char* p = ws + off;
    off += (bytes + 255) & ~(size_t)255;
    return p;
  };
  float*  partial = (float*)alloc(2048 * 2 * sizeof(float));
  bf16_t* WqT = (bf16_t*)alloc((size_t)1280 * 1280 * 2);
  bf16_t* WkT = (bf16_t*)alloc((size_t)1280 * 4096 * 2);  // WvT contiguous after
  bf16_t* WvT = (bf16_t*)alloc((size_t)1280 * 4096 * 2);
  bf16_t* WoT = (bf16_t*)alloc((size_t)1280 * 1280 * 2);
  bf16_t* h   = (bf16_t*)alloc((size_t)8192 * 1280 * 2);  // reused as attn_out
  bf16_t* enc = (bf16_t*)alloc((size_t)154 * 4096 * 2);
  bf16_t* qb  = (bf16_t*)alloc((size_t)8192 * 1280 * 2);
  bf16_t* kb  = (bf16_t*)alloc((size_t)154 * 1280 * 2);
  bf16_t* vb  = (bf16_t*)alloc((size_t)154 * 1280 * 2);
  float*  part = (float*)alloc((size_t)8 * 154 * 2560 * sizeof(float));

  // 1) prep: 4 weight transposes + gn_partial + layernorm
  k_prep<<<8922, 256, 0, stream>>>(x, text, lng, lnb, Wq, Wo, Wk, Wv,
                                   WqT, WoT, WkT, WvT, partial, enc);

  // 2) gn apply (finalize fused) + K/V split-K GEMM in one launch
  k_gnapply_kv<<<3200, 256, 0, stream>>>(x, partial, gng, gnb, h, enc, WkT, part);

  // 3) Q projection (128x64 proven) + fused kv_reduce tail blocks
  k_gemm_q<<<1665, 256, 0, stream>>>(h, WqT, bq, qb, part, bk, bv, kb, vb);

  // 4) attention (writes attn_out into h buffer)
  k_attn<<<dim3(64, 40), 256, 0, stream>>>(qb, kb, vb, h, sreg, msk, treg);

  // 5) output projection + residual + transpose to (B,C,S)
  k_gemm_o<<<1280, 256, 0, stream>>>(h, WoT, bo, x, out);
}

// Round 17
// 157.474 us; speedup vs baseline: 1.1489x; 1.0125x over previous
//
#include <hip/hip_runtime.h>

typedef __bf16 bf16_t;
typedef __bf16 bf16x8 __attribute__((ext_vector_type(8)));
typedef float  f32x4  __attribute__((ext_vector_type(4)));
typedef unsigned int u32x4 __attribute__((ext_vector_type(4)));

// problem constants
// B=2 C=1280 HEADS=20 DH=64 S=4096 L=77 ENC=4096 GROUPS=32 EPS=1e-5

// ---------------- fat prep kernel: 4 transposes + gn_partial + layernorm -----
__global__ __launch_bounds__(256) void k_prep(
    const float* __restrict__ x, const float* __restrict__ text,
    const float* __restrict__ lng, const float* __restrict__ lnb,
    const float* __restrict__ w0, const float* __restrict__ w1,
    const float* __restrict__ w2, const float* __restrict__ w3,
    bf16_t* __restrict__ o0, bf16_t* __restrict__ o1,
    bf16_t* __restrict__ o2, bf16_t* __restrict__ o3,
    float* __restrict__ partial, bf16_t* __restrict__ enc)
{
  __shared__ float smemf[64 * 33];
  const int bid = blockIdx.x;
  const int t   = threadIdx.x;

  if (bid < 6720) {
    int z, lb;
    if      (bid < 800)  { z = 0; lb = bid; }
    else if (bid < 1600) { z = 1; lb = bid - 800; }
    else if (bid < 4160) { z = 2; lb = bid - 1600; }
    else                 { z = 3; lb = bid - 4160; }
    const float* in  = (z == 0) ? w0 : (z == 1) ? w1 : (z == 2) ? w2 : w3;
    bf16_t*      out = (z == 0) ? o0 : (z == 1) ? o1 : (z == 2) ? o2 : o3;
    const int R  = (z < 2) ? 1280 : 4096;
    const int c0 = (lb % 40) * 32;
    const int r0 = (lb / 40) * 64;
    float (*tile)[33] = (float(*)[33])smemf;
#pragma unroll
    for (int it = 0; it < 8; ++it) {
      int r = it * 8 + (t >> 5), c = t & 31;
      tile[r][c] = in[(size_t)(r0 + r) * 1280 + c0 + c];
    }
    __syncthreads();
    const int oc  = t >> 3;
    const int seg = t & 7;
    bf16x8 o;
#pragma unroll
    for (int e = 0; e < 8; ++e) o[e] = (bf16_t)tile[seg * 8 + e][oc];
    *(bf16x8*)(out + (size_t)(c0 + oc) * R + r0 + seg * 8) = o;
  } else if (bid < 8768) {
    const int pb    = bid - 6720;
    const int bg    = pb >> 5;
    const int chunk = pb & 31;
    const float* p  = x + (size_t)bg * 163840 + (size_t)chunk * 5120;
    float s1 = 0.f, s2 = 0.f;
#pragma unroll
    for (int it = 0; it < 5; ++it) {
      float4 v = *(const float4*)(p + (size_t)(it * 256 + t) * 4);
      s1 += v.x + v.y + v.z + v.w;
      s2 += v.x * v.x + v.y * v.y + v.z * v.z + v.w * v.w;
    }
#pragma unroll
    for (int off = 32; off > 0; off >>= 1) {
      s1 += __shfl_down(s1, off);
      s2 += __shfl_down(s2, off);
    }
    float* r1 = smemf;
    float* r2 = smemf + 4;
    if ((t & 63) == 0) { r1[t >> 6] = s1; r2[t >> 6] = s2; }
    __syncthreads();
    if (t == 0) {
      partial[pb * 2]     = r1[0] + r1[1] + r1[2] + r1[3];
      partial[pb * 2 + 1] = r2[0] + r2[1] + r2[2] + r2[3];
    }
  } else {
    const int row = bid - 8768;
    const float* p = text + (size_t)row * 4096;
    float s1 = 0.f, s2 = 0.f;
    for (int i = t; i < 1024; i += 256) {
      float4 v = *(const float4*)(p + (size_t)i * 4);
      s1 += v.x + v.y + v.z + v.w;
      s2 += v.x * v.x + v.y * v.y + v.z * v.z + v.w * v.w;
    }
#pragma unroll
    for (int off = 32; off > 0; off >>= 1) {
      s1 += __shfl_down(s1, off);
      s2 += __shfl_down(s2, off);
    }
    float* r1 = smemf;
    float* r2 = smemf + 4;
    float* sh = smemf + 8;
    if ((t & 63) == 0) { r1[t >> 6] = s1; r2[t >> 6] = s2; }
    __syncthreads();
    if (t == 0) {
      float t1 = r1[0] + r1[1] + r1[2] + r1[3];
      float t2 = r2[0] + r2[1] + r2[2] + r2[3];
      const float invN = 1.0f / 4096.0f;
      float mu  = t1 * invN;
      float var = t2 * invN - mu * mu;
      sh[0] = mu;
      sh[1] = rsqrtf(var + 1e-5f);
    }
    __syncthreads();
    const float mu = sh[0], rs = sh[1];
    for (int i = t; i < 1024; i += 256) {
      float4 v  = *(const float4*)(p + (size_t)i * 4);
      float4 gg = *(const float4*)(lng + (size_t)i * 4);
      float4 bb = *(const float4*)(lnb + (size_t)i * 4);
      bf16_t* o = enc + (size_t)row * 4096 + (size_t)i * 4;
      o[0] = (bf16_t)((v.x - mu) * rs * gg.x + bb.x);
      o[1] = (bf16_t)((v.y - mu) * rs * gg.y + bb.y);
      o[2] = (bf16_t)((v.z - mu) * rs * gg.z + bb.z);
      o[3] = (bf16_t)((v.w - mu) * rs * gg.w + bb.w);
    }
  }
}

// ---------------- KV unsplit GEMM (bias fused, bf16 out) + gn_apply ----------
// blocks [0,80): K/V proj, K=4096 unsplit -> kb/vb ; blocks [80,2640): gn_apply
__global__ __launch_bounds__(256, 3) void k_kv_gn(
    const float* __restrict__ x, const float* __restrict__ partial,
    const float* __restrict__ gamma, const float* __restrict__ beta,
    bf16_t* __restrict__ h,
    const bf16_t* __restrict__ enc, const bf16_t* __restrict__ WkT,
    const float* __restrict__ bk, const float* __restrict__ bv,
    bf16_t* __restrict__ kb, bf16_t* __restrict__ vb)
{
  __shared__ alignas(16) char smraw[49152];
  const int bid = blockIdx.x;
  const int tid = threadIdx.x;

  if (bid >= 80) {
    // ---- GroupNorm apply + transpose ----
    float (*tile)[65] = (float(*)[65])smraw;
    float* sst = (float*)(smraw + 64 * 65 * sizeof(float));
    const int idx = bid - 80;
    const int s0 = (idx & 63) * 64;
    const int c0 = ((idx >> 6) % 20) * 64;
    const int b  = idx / 1280;
    {
      const int g = tid >> 3, j = tid & 7;
      const int base = ((b * 32 + g) * 32) * 2;
      float s1 = 0.f, s2 = 0.f;
#pragma unroll
      for (int k = 0; k < 4; ++k) {
        s1 += partial[base + (j + 8 * k) * 2];
        s2 += partial[base + (j + 8 * k) * 2 + 1];
      }
      s1 += __shfl_down(s1, 1); s2 += __shfl_down(s2, 1);
      s1 += __shfl_down(s1, 2); s2 += __shfl_down(s2, 2);
      s1 += __shfl_down(s1, 4); s2 += __shfl_down(s2, 4);
      if (j == 0) {
        const float invN = 1.0f / 163840.0f;
        float mu  = s1 * invN;
        float var = s2 * invN - mu * mu;
        sst[g * 2]     = mu;
        sst[g * 2 + 1] = rsqrtf(var + 1e-5f);
      }
    }
#pragma unroll
    for (int it = 0; it < 16; ++it) {
      int cl = it * 4 + (tid >> 6);
      int sl = tid & 63;
      tile[cl][sl] = x[((size_t)(b * 1280 + c0 + cl) << 12) + s0 + sl];
    }
    __syncthreads();
#pragma unroll
    for (int it = 0; it < 2; ++it) {
      int i  = it * 256 + tid;
      int sl = i >> 3;
      int cg = i & 7;
      bf16x8 o;
#pragma unroll
      for (int e = 0; e < 8; ++e) {
        int c  = c0 + cg * 8 + e;
        int g  = c / 40;
        float mu = sst[g * 2];
        float rs = sst[g * 2 + 1];
        o[e] = (bf16_t)((tile[cg * 8 + e][sl] - mu) * rs * gamma[c] + beta[c]);
      }
      *(bf16x8*)(h + (size_t)(b * 4096 + s0 + sl) * 1280 + c0 + cg * 8) = o;
    }
    return;
  }

  // ---- K/V merged projection, K=4096 unsplit ----
  bf16_t* smem = (bf16_t*)smraw;  // 48 KB
  const int lane = tid & 63;
  const int wv   = tid >> 6;
  const int wm   = wv >> 1, wn = wv & 1;
  const int m0   = (bid / 40) * 128;
  const int n0   = (bid % 40) * 64;
  const int lda  = 4096;

  f32x4 acc[4][2];
  const f32x4 fz = {0.f, 0.f, 0.f, 0.f};
#pragma unroll
  for (int i = 0; i < 4; ++i)
#pragma unroll
    for (int j = 0; j < 2; ++j) acc[i][j] = fz;

  auto stage = [&](int buf, int kt) {
    bf16_t* sA = smem + buf * 8192;
    bf16_t* sB = smem + 16384 + buf * 4096;
#pragma unroll
    for (int it = 0; it < 4; ++it) {
      int slot = it * 256 + tid;
      int row  = slot >> 3, ch = slot & 7;
      int grow = m0 + row; if (grow > 153) grow = 153;
      const bf16_t* ga = enc + (size_t)grow * lda + kt + ((ch ^ (row & 7)) << 3);
      __builtin_amdgcn_global_load_lds(
          (const __attribute__((address_space(1))) void*)ga,
          (__attribute__((address_space(3))) void*)((char*)sA + slot * 16),
          16, 0, 0);
    }
#pragma unroll
    for (int it = 0; it < 2; ++it) {
      int slot = it * 256 + tid;
      int row  = slot >> 3, ch = slot & 7;
      const bf16_t* gb = WkT + (size_t)(n0 + row) * lda + kt + ((ch ^ (row & 7)) << 3);
      __builtin_amdgcn_global_load_lds(
          (const __attribute__((address_space(1))) void*)gb,
          (__attribute__((address_space(3))) void*)((char*)sB + slot * 16),
          16, 0, 0);
    }
  };

  const int nt_k = 64;  // K=4096
  stage(0, 0);
  stage(1, 64);

  for (int t = 0; t < nt_k; ++t) {
    if (t + 1 < nt_k) { asm volatile("s_waitcnt vmcnt(6)" ::: "memory"); }
    else              { asm volatile("s_waitcnt vmcnt(0)" ::: "memory"); }
    __builtin_amdgcn_s_barrier();
    const char* pA = (const char*)(smem + (t & 1) * 8192);
    const char* pB = (const char*)(smem + 16384 + (t & 1) * 4096);
#pragma unroll
    for (int ks = 0; ks < 2; ++ks) {
      const int kb_ = ks * 64 + ((lane >> 4) << 4);
      bf16x8 af[4], bfg[2];
#pragma unroll
      for (int i = 0; i < 4; ++i) {
        int r = wm * 64 + i * 16 + (lane & 15);
        af[i] = *(const bf16x8*)(pA + r * 128 + (kb_ ^ ((r & 7) << 4)));
      }
#pragma unroll
      for (int j = 0; j < 2; ++j) {
        int c = wn * 32 + j * 16 + (lane & 15);
        bfg[j] = *(const bf16x8*)(pB + c * 128 + (kb_ ^ ((c & 7) << 4)));
      }
#pragma unroll
      for (int i = 0; i < 4; ++i)
#pragma unroll
        for (int j = 0; j < 2; ++j)
          acc[i][j] = __builtin_amdgcn_mfma_f32_16x16x32_bf16(af[i], bfg[j], acc[i][j], 0, 0, 0);
    }
    asm volatile("s_waitcnt lgkmcnt(0)" ::: "memory");
    __builtin_amdgcn_s_barrier();
    if (t + 2 < nt_k) stage(t & 1, (t + 2) * 64);
  }

#pragma unroll
  for (int i = 0; i < 4; ++i) {
    const int mrow = m0 + wm * 64 + i * 16 + ((lane >> 4) << 2);
#pragma unroll
    for (int j = 0; j < 2; ++j) {
      const int n = n0 + wn * 32 + j * 16 + (lane & 15);
      const float bs = (n < 1280) ? bk[n] : bv[n - 1280];
#pragma unroll
      for (int r = 0; r < 4; ++r)
        if (mrow + r < 154) {
          bf16_t val = (bf16_t)(acc[i][j][r] + bs);
          if (n < 1280) kb[(size_t)(mrow + r) * 1280 + n] = val;
          else          vb[(size_t)(mrow + r) * 1280 + n - 1280] = val;
        }
    }
  }
}

// ---------------- Q projection + FUSED attention -----------------------------
// 1280 blocks: block (mtile, head): GEMM q = h[128 rows] @ WqT[head cols] then
// attention for those 128 s-rows x head, writing attn_out to ao.
// GEMM inner loop = proven round-7 structure. Attn = proven k_attn body, with
// sQ filled from registers (swizzled scalar stores), looped over two 64-row
// halves (sP reused, barrier-protected).
__global__ __launch_bounds__(256, 3) void k_qattn(
    const bf16_t* __restrict__ A, const bf16_t* __restrict__ BT,
    const float* __restrict__ bq, const bf16_t* __restrict__ kbuf,
    const bf16_t* __restrict__ vbuf, bf16_t* __restrict__ ao,
    const float* __restrict__ size_reg, const int* __restrict__ mask,
    const float* __restrict__ treg)
{
  __shared__ alignas(16) char smraw[53248];  // 52 KB
  bf16_t* smem = (bf16_t*)smraw;
  const int tid  = threadIdx.x;
  const int lane = tid & 63;
  const int wv   = tid >> 6;
  const int wm   = wv >> 1, wn = wv & 1;

  const int nbid = (blockIdx.x & 7) * 160 + (blockIdx.x >> 3);
  const int m0   = (nbid / 20) * 128;
  const int head = nbid % 20;
  const int n0   = head * 64;
  const int lda  = 1280;

  f32x4 acc[4][2];
  const f32x4 fz = {0.f, 0.f, 0.f, 0.f};
#pragma unroll
  for (int i = 0; i < 4; ++i)
#pragma unroll
    for (int j = 0; j < 2; ++j) acc[i][j] = fz;

  auto stage = [&](int buf, int kt) {
    bf16_t* sA = smem + buf * 8192;
    bf16_t* sB = smem + 16384 + buf * 4096;
#pragma unroll
    for (int it = 0; it < 4; ++it) {
      int slot = it * 256 + tid;
      int row  = slot >> 3, ch = slot & 7;
      const bf16_t* ga = A + (size_t)(m0 + row) * lda + kt + ((ch ^ (row & 7)) << 3);
      __builtin_amdgcn_global_load_lds(
          (const __attribute__((address_space(1))) void*)ga,
          (__attribute__((address_space(3))) void*)((char*)sA + slot * 16),
          16, 0, 0);
    }
#pragma unroll
    for (int it = 0; it < 2; ++it) {
      int slot = it * 256 + tid;
      int row  = slot >> 3, ch = slot & 7;
      const bf16_t* gb = BT + (size_t)(n0 + row) * lda + kt + ((ch ^ (row & 7)) << 3);
      __builtin_amdgcn_global_load_lds(
          (const __attribute__((address_space(1))) void*)gb,
          (__attribute__((address_space(3))) void*)((char*)sB + slot * 16),
          16, 0, 0);
    }
  };

  const int nt_k = 20;
  stage(0, 0);
  stage(1, 64);

  for (int t = 0; t < nt_k; ++t) {
    if (t + 1 < nt_k) { asm volatile("s_waitcnt vmcnt(6)" ::: "memory"); }
    else              { asm volatile("s_waitcnt vmcnt(0)" ::: "memory"); }
    __builtin_amdgcn_s_barrier();
    const char* pA = (const char*)(smem + (t & 1) * 8192);
    const char* pB = (const char*)(smem + 16384 + (t & 1) * 4096);
#pragma unroll
    for (int ks = 0; ks < 2; ++ks) {
      const int kb_ = ks * 64 + ((lane >> 4) << 4);
      bf16x8 af[4], bfg[2];
#pragma unroll
      for (int i = 0; i < 4; ++i) {
        int r = wm * 64 + i * 16 + (lane & 15);
        af[i] = *(const bf16x8*)(pA + r * 128 + (kb_ ^ ((r & 7) << 4)));
      }
#pragma unroll
      for (int j = 0; j < 2; ++j) {
        int c = wn * 32 + j * 16 + (lane & 15);
        bfg[j] = *(const bf16x8*)(pB + c * 128 + (kb_ ^ ((c & 7) << 4)));
      }
#pragma unroll
      for (int i = 0; i < 4; ++i)
#pragma unroll
        for (int j = 0; j < 2; ++j)
          acc[i][j] = __builtin_amdgcn_mfma_f32_16x16x32_bf16(af[i], bfg[j], acc[i][j], 0, 0, 0);
    }
    asm volatile("s_waitcnt lgkmcnt(0)" ::: "memory");
    __builtin_amdgcn_s_barrier();
    if (t + 2 < nt_k) stage(t & 1, (t + 2) * 64);
  }

  // ---- attention phase: LDS layout (all reads of GEMM tiles are done) ----
  bf16_t* sQ  = (bf16_t*)smraw;             // [128] rows x 128B, swizzled
  bf16_t* sK  = (bf16_t*)(smraw + 16384);   // [80] rows x 128B, swizzled
  bf16_t* sVT = (bf16_t*)(smraw + 26624);   // [64][104]
  bf16_t* sP  = (bf16_t*)(smraw + 39936);   // [4][16][104]
  const int b    = m0 >> 12;
  const int sloc = m0 & 4095;
  const int ntok = lane & 15;
  const u32x4 uz = {0u, 0u, 0u, 0u};

  // q + bias -> sQ (swizzled scalar stores)
#pragma unroll
  for (int j = 0; j < 2; ++j) {
    const int dh = wn * 32 + j * 16 + (lane & 15);
    const float bs = bq[n0 + dh];
#pragma unroll
    for (int i = 0; i < 4; ++i) {
      const int rl = wm * 64 + i * 16 + ((lane >> 4) << 2);
#pragma unroll
      for (int r = 0; r < 4; ++r) {
        const int row = rl + r;
        const int byte = row * 128 + ((((dh >> 3) ^ (row & 7)) << 4)) + ((dh & 7) * 2);
        *(bf16_t*)((char*)sQ + byte) = (bf16_t)(acc[i][j][r] + bs);
      }
    }
  }
  // zero sVT pad + sP
  for (int i = tid; i < 832; i += 256) ((u32x4*)sVT)[i] = uz;
  for (int i = tid; i < 832; i += 256) ((u32x4*)sP)[i]  = uz;
  // stage K (swizzled rows, rows>=77 zero)
  const size_t kvbase = ((size_t)(b * 77)) * 1280 + head * 64;
  for (int slot = tid; slot < 640; slot += 256) {
    int tok = slot >> 3, ch = slot & 7;
    u32x4 d = uz;
    if (tok < 77)
      d = *(const u32x4*)(kbuf + kvbase + (size_t)tok * 1280 + ((ch ^ (tok & 7)) << 3));
    *(u32x4*)((char*)sK + slot * 16) = d;
  }
  __syncthreads();
  // V^T fill
  for (int e = tid; e < 77 * 64; e += 256) {
    int tok = e >> 6, dh = e & 63;
    sVT[dh * 104 + tok] = vbuf[kvbase + (size_t)tok * 1280 + dh];
  }
  __syncthreads();

  for (int h2 = 0; h2 < 2; ++h2) {
    if (h2) __syncthreads();  // protect sP reuse across halves

    f32x4 sim[5];
#pragma unroll
    for (int nf = 0; nf < 5; ++nf) sim[nf] = fz;
    const int qrow = h2 * 64 + wv * 16 + (lane & 15);
#pragma unroll
    for (int ks = 0; ks < 2; ++ks) {
      const int kb_ = ks * 64 + ((lane >> 4) << 4);
      bf16x8 aq = *(const bf16x8*)((const char*)sQ + qrow * 128 + (kb_ ^ ((qrow & 7) << 4)));
#pragma unroll
      for (int nf = 0; nf < 5; ++nf) {
        int tok = nf * 16 + ntok;
        bf16x8 bk_ = *(const bf16x8*)((const char*)sK + tok * 128 + (kb_ ^ ((tok & 7) << 4)));
        sim[nf] = __builtin_amdgcn_mfma_f32_16x16x32_bf16(aq, bk_, sim[nf], 0, 0, 0);
      }
    }

    float vv[5][4];
#pragma unroll
    for (int nf = 0; nf < 5; ++nf)
#pragma unroll
      for (int r = 0; r < 4; ++r) vv[nf][r] = sim[nf][r] * 0.125f;

    const int rbase = sloc + h2 * 64 + wv * 16 + ((lane >> 4) << 2);

    if (b == 1) {
      const float tr = treg[0];
#pragma unroll
      for (int r = 0; r < 4; ++r) {
        float mx = -1e30f, mn = 1e30f;
#pragma unroll
        for (int nf = 0; nf < 5; ++nf)
          if (nf * 16 + ntok < 77) { mx = fmaxf(mx, vv[nf][r]); mn = fminf(mn, vv[nf][r]); }
#pragma unroll
        for (int m = 1; m < 16; m <<= 1) {
          mx = fmaxf(mx, __shfl_xor(mx, m));
          mn = fminf(mn, __shfl_xor(mn, m));
        }
        const int srow = rbase + r;
#pragma unroll
        for (int nf = 0; nf < 5; ++nf) {
          int l = nf * 16 + ntok;
          if (l < 77) {
            float w  = size_reg[srow * 77 + l] * tr;
            int   mk = mask[srow * 77 + l];
            float v  = vv[nf][r];
            vv[nf][r] = (mk > 0) ? v + w * (mx - v) : v - w * (v - mn);
          }
        }
      }
    }

#pragma unroll
    for (int r = 0; r < 4; ++r) {
      float mx = -1e30f;
#pragma unroll
      for (int nf = 0; nf < 5; ++nf)
        if (nf * 16 + ntok < 77) mx = fmaxf(mx, vv[nf][r]);
#pragma unroll
      for (int m = 1; m < 16; m <<= 1) mx = fmaxf(mx, __shfl_xor(mx, m));
      float p[5]; float sm = 0.f;
#pragma unroll
      for (int nf = 0; nf < 5; ++nf) {
        bool val = (nf * 16 + ntok) < 77;
        p[nf] = val ? __expf(vv[nf][r] - mx) : 0.f;
        sm += p[nf];
      }
#pragma unroll
      for (int m = 1; m < 16; m <<= 1) sm += __shfl_xor(sm, m);
      const float inv = 1.0f / sm;
      const int prow = ((lane >> 4) << 2) + r;
#pragma unroll
      for (int nf = 0; nf < 5; ++nf)
        sP[wv * 1664 + prow * 104 + nf * 16 + ntok] = (bf16_t)(p[nf] * inv);
    }
    __syncthreads();

    f32x4 o[4];
#pragma unroll
    for (int fd = 0; fd < 4; ++fd) o[fd] = fz;
#pragma unroll
    for (int ks = 0; ks < 3; ++ks) {
      const int kb_ = ks * 64 + ((lane >> 4) << 4);
      bf16x8 ap = *(const bf16x8*)((const char*)sP + wv * 3328 + (lane & 15) * 208 + kb_);
#pragma unroll
      for (int fd = 0; fd < 4; ++fd) {
        bf16x8 bv_ = *(const bf16x8*)((const char*)sVT + (fd * 16 + (lane & 15)) * 208 + kb_);
        o[fd] = __builtin_amdgcn_mfma_f32_16x16x32_bf16(ap, bv_, o[fd], 0, 0, 0);
      }
    }
    const size_t obase =
        ((size_t)(m0 + h2 * 64 + wv * 16 + ((lane >> 4) << 2))) * 1280 + head * 64;
#pragma unroll
    for (int fd = 0; fd < 4; ++fd)
#pragma unroll
      for (int r = 0; r < 4; ++r)
        ao[obase + (size_t)r * 1280 + fd * 16 + (lane & 15)] = (bf16_t)o[fd][r];
  }
}

// ---------------- O-proj GEMM (round-7/12 proven, EPI2) ----------------------
__global__ __launch_bounds__(256, 3) void k_gemm_o(
    const bf16_t* __restrict__ A, const bf16_t* __restrict__ BT,
    const float* __restrict__ bias, const float* __restrict__ xres,
    float* __restrict__ dout)
{
  __shared__ alignas(16) bf16_t smem[24576];
  const int tid  = threadIdx.x;
  const int lane = tid & 63;
  const int wv   = tid >> 6;
  const int wm   = wv >> 1, wn = wv & 1;

  const int nbid = (blockIdx.x & 7) * 160 + (blockIdx.x >> 3);
  const int m0   = (nbid / 20) * 128;
  const int n0   = (nbid % 20) * 64;
  const int lda  = 1280;

  f32x4 acc[4][2];
  const f32x4 fz = {0.f, 0.f, 0.f, 0.f};
#pragma unroll
  for (int i = 0; i < 4; ++i)
#pragma unroll
    for (int j = 0; j < 2; ++j) acc[i][j] = fz;

  auto stage = [&](int buf, int kt) {
    bf16_t* sA = smem + buf * 8192;
    bf16_t* sB = smem + 16384 + buf * 4096;
#pragma unroll
    for (int it = 0; it < 4; ++it) {
      int slot = it * 256 + tid;
      int row  = slot >> 3, ch = slot & 7;
      const bf16_t* ga = A + (size_t)(m0 + row) * lda + kt + ((ch ^ (row & 7)) << 3);
      __builtin_amdgcn_global_load_lds(
          (const __attribute__((address_space(1))) void*)ga,
          (__attribute__((address_space(3))) void*)((char*)sA + slot * 16),
          16, 0, 0);
    }
#pragma unroll
    for (int it = 0; it < 2; ++it) {
      int slot = it * 256 + tid;
      int row  = slot >> 3, ch = slot & 7;
      const bf16_t* gb = BT + (size_t)(n0 + row) * lda + kt + ((ch ^ (row & 7)) << 3);
      __builtin_amdgcn_global_load_lds(
          (const __attribute__((address_space(1))) void*)gb,
          (__attribute__((address_space(3))) void*)((char*)sB + slot * 16),
          16, 0, 0);
    }
  };

  const int nt_k = 20;
  stage(0, 0);
  stage(1, 64);

  for (int t = 0; t < nt_k; ++t) {
    if (t + 1 < nt_k) { asm volatile("s_waitcnt vmcnt(6)" ::: "memory"); }
    else              { asm volatile("s_waitcnt vmcnt(0)" ::: "memory"); }
    __builtin_amdgcn_s_barrier();
    const char* pA = (const char*)(smem + (t & 1) * 8192);
    const char* pB = (const char*)(smem + 16384 + (t & 1) * 4096);
#pragma unroll
    for (int ks = 0; ks < 2; ++ks) {
      const int kb_ = ks * 64 + ((lane >> 4) << 4);
      bf16x8 af[4], bfg[2];
#pragma unroll
      for (int i = 0; i < 4; ++i) {
        int r = wm * 64 + i * 16 + (lane & 15);
        af[i] = *(const bf16x8*)(pA + r * 128 + (kb_ ^ ((r & 7) << 4)));
      }
#pragma unroll
      for (int j = 0; j < 2; ++j) {
        int c = wn * 32 + j * 16 + (lane & 15);
        bfg[j] = *(const bf16x8*)(pB + c * 128 + (kb_ ^ ((c & 7) << 4)));
      }
#pragma unroll
      for (int i = 0; i < 4; ++i)
#pragma unroll
        for (int j = 0; j < 2; ++j)
          acc[i][j] = __builtin_amdgcn_mfma_f32_16x16x32_bf16(af[i], bfg[j], acc[i][j], 0, 0, 0);
    }
    asm volatile("s_waitcnt lgkmcnt(0)" ::: "memory");
    __builtin_amdgcn_s_barrier();
    if (t + 2 < nt_k) stage(t & 1, (t + 2) * 64);
  }

#pragma unroll
  for (int i = 0; i < 4; ++i) {
    const int mrow = m0 + wm * 64 + i * 16 + ((lane >> 4) << 2);
    const int b = mrow >> 12, s = mrow & 4095;
#pragma unroll
    for (int j = 0; j < 2; ++j) {
      const int n = n0 + wn * 32 + j * 16 + (lane & 15);
      const size_t off = ((size_t)(b * 1280 + n) << 12) + s;
      const float bs = bias[n];
      const float4 xr = *(const float4*)(xres + off);
      float4 o;
      o.x = acc[i][j][0] + bs + xr.x;
      o.y = acc[i][j][1] + bs + xr.y;
      o.z = acc[i][j][2] + bs + xr.z;
      o.w = acc[i][j][3] + bs + xr.w;
      *(float4*)(dout + off) = o;
    }
  }
}

// ---------------- host launch ----------------
extern "C" void kernel_launch(void* const* d_in, const int* in_sizes, int n_in,
                              void* d_out, int out_size, void* d_ws, size_t ws_size,
                              hipStream_t stream)
{
  const float* x    = (const float*)d_in[0];
  const float* text = (const float*)d_in[1];
  const float* gng  = (const float*)d_in[2];
  const float* gnb  = (const float*)d_in[3];
  const float* lng  = (const float*)d_in[4];
  const float* lnb  = (const float*)d_in[5];
  const float* Wq   = (const float*)d_in[6];
  const float* bq   = (const float*)d_in[7];
  const float* Wk   = (const float*)d_in[8];
  const float* bk   = (const float*)d_in[9];
  const float* Wv   = (const float*)d_in[10];
  const float* bv   = (const float*)d_in[11];
  const float* Wo   = (const float*)d_in[12];
  const float* bo   = (const float*)d_in[13];
  const float* sreg = (const float*)d_in[14];
  const float* treg = (const float*)d_in[15];
  const int*   msk  = (const int*)d_in[16];
  float* out = (float*)d_out;

  char* ws = (char*)d_ws;
  size_t off = 0;
  auto alloc = [&](size_t bytes) {
    char* p = ws + off;
    off += (bytes + 255) & ~(size_t)255;
    return p;
  };
  float*  partial = (float*)alloc(2048 * 2 * sizeof(float));
  bf16_t* WqT = (bf16_t*)alloc((size_t)1280 * 1280 * 2);
  bf16_t* WkT = (bf16_t*)alloc((size_t)1280 * 4096 * 2);  // WvT contiguous after
  bf16_t* WvT = (bf16_t*)alloc((size_t)1280 * 4096 * 2);
  bf16_t* WoT = (bf16_t*)alloc((size_t)1280 * 1280 * 2);
  bf16_t* h   = (bf16_t*)alloc((size_t)8192 * 1280 * 2);
  bf16_t* enc = (bf16_t*)alloc((size_t)154 * 4096 * 2);
  bf16_t* att = (bf16_t*)alloc((size_t)8192 * 1280 * 2);  // attn output
  bf16_t* kb  = (bf16_t*)alloc((size_t)154 * 1280 * 2);
  bf16_t* vb  = (bf16_t*)alloc((size_t)154 * 1280 * 2);

  // 1) prep: 4 weight transposes + gn_partial + layernorm
  k_prep<<<8922, 256, 0, stream>>>(x, text, lng, lnb, Wq, Wo, Wk, Wv,
                                   WqT, WoT, WkT, WvT, partial, enc);

  // 2) KV unsplit GEMM (first) + gn apply (finalize fused)
  k_kv_gn<<<2640, 256, 0, stream>>>(x, partial, gng, gnb, h, enc, WkT,
                                    bk, bv, kb, vb);

  // 3) Q projection + fused attention -> att
  k_qattn<<<1280, 256, 0, stream>>>(h, WqT, bq, kb, vb, att, sreg, msk, treg);

  // 4) output projection + residual + transpose to (B,C,S)
  k_gemm_o<<<1280, 256, 0, stream>>>(att, WoT, bo, x, out);
}